// Round 1
// baseline (2002.587 us; speedup 1.0000x reference)
//
#include <hip/hip_runtime.h>

#define B_  2
#define C_  192
#define L_  4096
#define NH_ 8
#define HD_ 24
#define C3_ 576
#define TK_ 32

// ---------------------------------------------------------------------------
// Per-pixel linear (1x1 conv): out[b][og*8+j][l] = bias + sum_c w[o][c]*a[b][c][l]
// a is [B][192][L] (channel-major, l contiguous). Block: 8 outputs x 256 l.
// ---------------------------------------------------------------------------
__global__ __launch_bounds__(256) void lin_kernel(const float* __restrict__ a,
                                                  const float* __restrict__ w,
                                                  const float* __restrict__ bias,
                                                  float* __restrict__ out, int OC) {
    __shared__ float wl[8][C_];
    const int og  = blockIdx.x;
    const int b   = blockIdx.y >> 4;
    const int lt  = blockIdx.y & 15;
    const int tid = threadIdx.x;

    for (int e = tid; e < 8 * C_; e += 256) {
        wl[e / C_][e % C_] = w[og * 8 * C_ + e];
    }
    __syncthreads();

    const int l = lt * 256 + tid;
    float acc[8];
#pragma unroll
    for (int j = 0; j < 8; ++j) acc[j] = bias[og * 8 + j];

    const float* ap = a + (size_t)b * C_ * L_ + l;
#pragma unroll 2
    for (int c = 0; c < C_; ++c) {
        const float xv = ap[(size_t)c * L_];
#pragma unroll
        for (int j = 0; j < 8; ++j) acc[j] = fmaf(wl[j][c], xv, acc[j]);
    }

    float* op = out + ((size_t)b * OC + og * 8) * L_ + l;
#pragma unroll
    for (int j = 0; j < 8; ++j) op[(size_t)j * L_] = acc[j];
}

// ---------------------------------------------------------------------------
// Flash attention, fp32 vector. One thread = one q row. Block = 256 rows,
// one (b, head). K/V tiles staged in LDS (broadcast reads), mask read as
// float4 straight from global (each thread consumes full cache lines).
// qkv layout: [B][576][L]; q at channel h*24+d, k at 192+..., v at 384+...
// ---------------------------------------------------------------------------
__global__ __launch_bounds__(256) void attn_kernel(const float* __restrict__ qkv,
                                                   const float* __restrict__ mask,
                                                   float* __restrict__ out) {
    const int qt  = blockIdx.x;   // 0..15
    const int h   = blockIdx.y;   // 0..7
    const int b   = blockIdx.z;   // 0..1
    const int tid = threadIdx.x;
    const int l   = qt * 256 + tid;

    __shared__ float k_lds[HD_][TK_];
    __shared__ float v_lds[HD_][TK_];

    const float* qbase = qkv + (size_t)b * C3_ * L_;
    const float* kbase = qbase + (size_t)(C_ + h * HD_) * L_;
    const float* vbase = qbase + (size_t)(2 * C_ + h * HD_) * L_;
    const float* mrow  = mask + ((size_t)b * L_ + l) * L_;

    const float scale = 0.35355339059327373f;  // num_heads^-0.5
    float q[HD_];
#pragma unroll
    for (int d = 0; d < HD_; ++d)
        q[d] = qbase[(size_t)(h * HD_ + d) * L_ + l] * scale;

    float m = -1e30f, s = 0.f;
    float acc[HD_];
#pragma unroll
    for (int d = 0; d < HD_; ++d) acc[d] = 0.f;

    for (int k0 = 0; k0 < L_; k0 += TK_) {
        __syncthreads();
        // stage K/V tile (768 elements each, 3 per thread)
#pragma unroll
        for (int i = 0; i < 3; ++i) {
            const int e = tid + i * 256;
            const int d = e / TK_, j = e % TK_;
            k_lds[d][j] = kbase[(size_t)d * L_ + k0 + j];
            v_lds[d][j] = vbase[(size_t)d * L_ + k0 + j];
        }
        __syncthreads();

        // p[j] starts as mask value, accumulates scale*q.k
        float p[TK_];
        const float4* m4p = (const float4*)(mrow + k0);
#pragma unroll
        for (int j4 = 0; j4 < TK_ / 4; ++j4) {
            const float4 mv = m4p[j4];
            p[j4 * 4 + 0] = mv.x;
            p[j4 * 4 + 1] = mv.y;
            p[j4 * 4 + 2] = mv.z;
            p[j4 * 4 + 3] = mv.w;
        }
#pragma unroll
        for (int d = 0; d < HD_; ++d) {
            const float4* kr = (const float4*)(&k_lds[d][0]);
            const float qd = q[d];
#pragma unroll
            for (int j4 = 0; j4 < TK_ / 4; ++j4) {
                const float4 kv = kr[j4];
                p[j4 * 4 + 0] = fmaf(qd, kv.x, p[j4 * 4 + 0]);
                p[j4 * 4 + 1] = fmaf(qd, kv.y, p[j4 * 4 + 1]);
                p[j4 * 4 + 2] = fmaf(qd, kv.z, p[j4 * 4 + 2]);
                p[j4 * 4 + 3] = fmaf(qd, kv.w, p[j4 * 4 + 3]);
            }
        }

        float tmax = p[0];
#pragma unroll
        for (int j = 1; j < TK_; ++j) tmax = fmaxf(tmax, p[j]);
        const float newm = fmaxf(m, tmax);
        const float r = __expf(m - newm);

        float ls = 0.f;
#pragma unroll
        for (int j = 0; j < TK_; ++j) {
            p[j] = __expf(p[j] - newm);
            ls += p[j];
        }
        s = s * r + ls;

#pragma unroll
        for (int d = 0; d < HD_; ++d) {
            float av = acc[d] * r;
            const float4* vr = (const float4*)(&v_lds[d][0]);
#pragma unroll
            for (int j4 = 0; j4 < TK_ / 4; ++j4) {
                const float4 vv = vr[j4];
                av = fmaf(p[j4 * 4 + 0], vv.x, av);
                av = fmaf(p[j4 * 4 + 1], vv.y, av);
                av = fmaf(p[j4 * 4 + 2], vv.z, av);
                av = fmaf(p[j4 * 4 + 3], vv.w, av);
            }
            acc[d] = av;
        }
        m = newm;
    }

    const float inv = 1.f / s;
    float* op = out + ((size_t)b * C_ + h * HD_) * L_ + l;
#pragma unroll
    for (int d = 0; d < HD_; ++d) op[(size_t)d * L_] = acc[d] * inv;
}

// ---------------------------------------------------------------------------
extern "C" void kernel_launch(void* const* d_in, const int* in_sizes, int n_in,
                              void* d_out, int out_size, void* d_ws, size_t ws_size,
                              hipStream_t stream) {
    const float* x      = (const float*)d_in[0];
    const float* mask   = (const float*)d_in[1];
    const float* w_qkv  = (const float*)d_in[2];
    const float* b_qkv  = (const float*)d_in[3];
    const float* w_proj = (const float*)d_in[4];
    const float* b_proj = (const float*)d_in[5];
    float* out = (float*)d_out;

    float* ws_qkv = (float*)d_ws;                          // B*576*L floats
    float* ws_att = ws_qkv + (size_t)B_ * C3_ * L_;        // B*192*L floats

    // QKV projection: 72 output-groups x (B * L/256) tiles
    lin_kernel<<<dim3(72, 32), 256, 0, stream>>>(x, w_qkv, b_qkv, ws_qkv, C3_);
    // Flash attention: grid (qtile, head, batch)
    attn_kernel<<<dim3(16, NH_, B_), 256, 0, stream>>>(ws_qkv, mask, ws_att);
    // Output projection straight into d_out
    lin_kernel<<<dim3(24, 32), 256, 0, stream>>>(ws_att, w_proj, b_proj, out, C_);
}

// Round 3
// 380.522 us; speedup vs baseline: 5.2627x; 5.2627x over previous
//
#include <hip/hip_runtime.h>

#define B_  2
#define C_  192
#define L_  4096
#define NH_ 8
#define HD_ 24
#define C3_ 576

typedef _Float16 f16;
typedef __attribute__((ext_vector_type(8))) f16 f16x8;
typedef __attribute__((ext_vector_type(16))) float f32x16;

__device__ __forceinline__ int pk2(float a, float b) {
    union { __fp16 h __attribute__((ext_vector_type(2))); int i; } u;
    u.h = __builtin_amdgcn_cvt_pkrtz(a, b);
    return u.i;
}

union Frag { f16x8 v; int i[4]; };

// ---------------------------------------------------------------------------
// Per-pixel linear (1x1 conv): out[b][og*8+j][l] = bias + sum_c w[o][c]*a[b][c][l]
// ---------------------------------------------------------------------------
__global__ __launch_bounds__(256) void lin_kernel(const float* __restrict__ a,
                                                  const float* __restrict__ w,
                                                  const float* __restrict__ bias,
                                                  float* __restrict__ out, int OC) {
    __shared__ float wl[8][C_];
    const int og  = blockIdx.x;
    const int b   = blockIdx.y >> 4;
    const int lt  = blockIdx.y & 15;
    const int tid = threadIdx.x;

    for (int e = tid; e < 8 * C_; e += 256) {
        wl[e / C_][e % C_] = w[og * 8 * C_ + e];
    }
    __syncthreads();

    const int l = lt * 256 + tid;
    float acc[8];
#pragma unroll
    for (int j = 0; j < 8; ++j) acc[j] = bias[og * 8 + j];

    const float* ap = a + (size_t)b * C_ * L_ + l;
#pragma unroll 2
    for (int c = 0; c < C_; ++c) {
        const float xv = ap[(size_t)c * L_];
#pragma unroll
        for (int j = 0; j < 8; ++j) acc[j] = fmaf(wl[j][c], xv, acc[j]);
    }

    float* op = out + ((size_t)b * OC + og * 8) * L_ + l;
#pragma unroll
    for (int j = 0; j < 8; ++j) op[(size_t)j * L_] = acc[j];
}

// ---------------------------------------------------------------------------
// MFMA fp16 flash attention, swapped-operand (T12) structure.
// Block = 256 threads = 4 waves; each wave owns 32 q-rows of one (b,h).
// Per 32-key tile:  S^T = mfma(K, Q^T) + mask(C-init)  [32x32x16_f16 x2]
//                   online softmax fully in-register (qrow = lane&31)
//                   O^T += mfma(V^T, P^T)               [32x32x16_f16 x2]
// K LDS: half2 over d-pairs   k_lds[dp][key]   (dp 12..15 zero pad)
// V LDS: half2 over key-pairs v_lds[kp][d]     (d 24..31 zero pad)
// ---------------------------------------------------------------------------
__global__ __launch_bounds__(256) void attn_mfma(const float* __restrict__ qkv,
                                                 const float* __restrict__ mask,
                                                 float* __restrict__ out) {
    const int tid  = threadIdx.x;
    const int lane = tid & 63;
    const int wid  = tid >> 6;
    const int hi   = lane >> 5;
    const int lq   = lane & 31;
    const int h    = blockIdx.y;
    const int b    = blockIdx.z;
    const int qrow = blockIdx.x * 128 + wid * 32 + lq;

    __shared__ int k_lds[16][32];
    __shared__ int v_lds[16][32];

    // zero the pad regions once (never touched in the loop)
    if (tid < 128) {
        k_lds[12 + (tid >> 5)][tid & 31] = 0;
        v_lds[tid & 15][24 + (tid >> 4)] = 0;
    }

    const float* qb   = qkv + (size_t)b * C3_ * L_;
    const float* kb   = qb + (size_t)(C_ + h * HD_) * L_;
    const float* vb   = qb + (size_t)(2 * C_ + h * HD_) * L_;
    const float* mrow = mask + ((size_t)b * L_ + qrow) * L_;

    // Q fragment (B-operand of QK^T), scale folded in. Held for all tiles.
    const float scale = 0.35355339059327373f;  // num_heads^-0.5
    int bq[8];
#pragma unroll
    for (int s = 0; s < 2; ++s)
#pragma unroll
        for (int t = 0; t < 4; ++t) {
            const int d0 = 16 * s + 8 * hi + 2 * t;
            float qa = 0.f, qc = 0.f;
            if (d0 < HD_) {
                qa = qb[(size_t)(h * HD_ + d0) * L_ + qrow] * scale;
                qc = qb[(size_t)(h * HD_ + d0 + 1) * L_ + qrow] * scale;
            }
            bq[s * 4 + t] = pk2(qa, qc);
        }

    f32x16 o;
#pragma unroll
    for (int i = 0; i < 16; ++i) o[i] = 0.f;
    float mrun = -1e30f, srun = 0.f;

    for (int kk = 0; kk < L_; kk += 32) {
        __syncthreads();
        // ---- stage K/V tile (e in [0,384): tid, and tid+256 for tid<128) ----
        {
            int e = tid;
            int dp = e >> 5, key = e & 31;
            float ka = kb[(size_t)(2 * dp) * L_ + kk + key];
            float kc = kb[(size_t)(2 * dp + 1) * L_ + kk + key];
            k_lds[dp][key] = pk2(ka, kc);
            int d = e >> 4, kp = e & 15;
            float2 vv = *(const float2*)(vb + (size_t)d * L_ + kk + 2 * kp);
            v_lds[kp][d] = pk2(vv.x, vv.y);
            if (tid < 128) {
                e = tid + 256;
                dp = e >> 5; key = e & 31;
                ka = kb[(size_t)(2 * dp) * L_ + kk + key];
                kc = kb[(size_t)(2 * dp + 1) * L_ + kk + key];
                k_lds[dp][key] = pk2(ka, kc);
                d = e >> 4; kp = e & 15;
                vv = *(const float2*)(vb + (size_t)d * L_ + kk + 2 * kp);
                v_lds[kp][d] = pk2(vv.x, vv.y);
            }
        }
        // ---- mask loads (C-init), overlap staging latency ----
        const float4* mp = (const float4*)(mrow + kk + 4 * hi);
        const float4 m0 = mp[0], m1 = mp[2], m2 = mp[4], m3 = mp[6];
        __syncthreads();

        // ---- QK^T (swapped): c[reg] = S^T[key][qrow], key=(reg&3)+8(reg>>2)+4hi
        f32x16 c;
        c[0] = m0.x; c[1] = m0.y; c[2]  = m0.z; c[3]  = m0.w;
        c[4] = m1.x; c[5] = m1.y; c[6]  = m1.z; c[7]  = m1.w;
        c[8] = m2.x; c[9] = m2.y; c[10] = m2.z; c[11] = m2.w;
        c[12] = m3.x; c[13] = m3.y; c[14] = m3.z; c[15] = m3.w;

        Frag ka0, ka1, qf0, qf1;
#pragma unroll
        for (int t = 0; t < 4; ++t) {
            ka0.i[t] = k_lds[4 * hi + t][lq];
            ka1.i[t] = k_lds[8 + 4 * hi + t][lq];
            qf0.i[t] = bq[t];
            qf1.i[t] = bq[4 + t];
        }
        c = __builtin_amdgcn_mfma_f32_32x32x16_f16(ka0.v, qf0.v, c, 0, 0, 0);
        c = __builtin_amdgcn_mfma_f32_32x32x16_f16(ka1.v, qf1.v, c, 0, 0, 0);

        // ---- online softmax (per q-row; lane pair l, l^32) ----
        float pmax = c[0];
#pragma unroll
        for (int i = 1; i < 16; ++i) pmax = fmaxf(pmax, c[i]);
        pmax = fmaxf(pmax, __shfl_xor(pmax, 32));
        const float newm = fmaxf(mrun, pmax);
        const float r = __expf(mrun - newm);
        float ls = 0.f;
#pragma unroll
        for (int i = 0; i < 16; ++i) {
            const float pv = __expf(c[i] - newm);
            c[i] = pv;
            ls += pv;
        }
        ls += __shfl_xor(ls, 32);
        srun = srun * r + ls;
        mrun = newm;
#pragma unroll
        for (int i = 0; i < 16; ++i) o[i] *= r;

        // ---- pack P -> f16, exchange halves (T12 pattern via shfl_xor 32) ----
        int w1[4], w2[4], s1[4], s2[4];
#pragma unroll
        for (int q = 0; q < 4; ++q) {
            w1[q] = pk2(c[4 * q], c[4 * q + 1]);
            w2[q] = pk2(c[4 * q + 2], c[4 * q + 3]);
        }
#pragma unroll
        for (int q = 0; q < 4; ++q) {
            s1[q] = __shfl_xor(w1[q], 32);
            s2[q] = __shfl_xor(w2[q], 32);
        }

        // ---- PV (swapped): O^T += V^T · P^T ----
#pragma unroll
        for (int s = 0; s < 2; ++s) {
            const int q = 2 * s + hi;
            Frag pb, va;
            pb.i[0] = hi ? s1[q] : w1[q];
            pb.i[1] = hi ? s2[q] : w2[q];
            pb.i[2] = hi ? w1[q] : s1[q];
            pb.i[3] = hi ? w2[q] : s2[q];
#pragma unroll
            for (int t = 0; t < 4; ++t) va.i[t] = v_lds[8 * s + 4 * hi + t][lq];
            o = __builtin_amdgcn_mfma_f32_32x32x16_f16(va.v, pb.v, o, 0, 0, 0);
        }
    }

    // ---- epilogue: O^T regs hold d=(reg&3)+8(reg>>2)+4hi for qrow ----
    const float inv = 1.f / srun;
    float* op = out + ((size_t)b * C_ + h * HD_) * L_ + qrow;
#pragma unroll
    for (int i = 0; i < 16; ++i) {
        const int d = (i & 3) + 8 * (i >> 2) + 4 * hi;
        if (d < HD_) op[(size_t)d * L_] = o[i] * inv;
    }
}

// ---------------------------------------------------------------------------
extern "C" void kernel_launch(void* const* d_in, const int* in_sizes, int n_in,
                              void* d_out, int out_size, void* d_ws, size_t ws_size,
                              hipStream_t stream) {
    const float* x      = (const float*)d_in[0];
    const float* mask   = (const float*)d_in[1];
    const float* w_qkv  = (const float*)d_in[2];
    const float* b_qkv  = (const float*)d_in[3];
    const float* w_proj = (const float*)d_in[4];
    const float* b_proj = (const float*)d_in[5];
    float* out = (float*)d_out;

    float* ws_qkv = (float*)d_ws;                       // B*576*L floats
    float* ws_att = ws_qkv + (size_t)B_ * C3_ * L_;     // B*192*L floats

    lin_kernel<<<dim3(72, 32), 256, 0, stream>>>(x, w_qkv, b_qkv, ws_qkv, C3_);
    attn_mfma<<<dim3(32, NH_, B_), 256, 0, stream>>>(ws_qkv, mask, ws_att);
    lin_kernel<<<dim3(24, 32), 256, 0, stream>>>(ws_att, w_proj, b_proj, out, C_);
}

// Round 4
// 344.713 us; speedup vs baseline: 5.8094x; 1.1039x over previous
//
#include <hip/hip_runtime.h>

#define B_  2
#define C_  192
#define L_  4096
#define NH_ 8
#define HD_ 24
#define C3_ 576
#define KV_ 64
#define NT_ (L_ / KV_)

typedef _Float16 f16;
typedef __attribute__((ext_vector_type(8))) f16 f16x8;
typedef __attribute__((ext_vector_type(16))) float f32x16;

__device__ __forceinline__ int pk2(float a, float b) {
    union { __fp16 h __attribute__((ext_vector_type(2))); int i; } u;
    u.h = __builtin_amdgcn_cvt_pkrtz(a, b);
    return u.i;
}
__device__ __forceinline__ int pk2_rte(float a, float b) {
    union { f16 h[2]; int i; } u;
    u.h[0] = (f16)a; u.h[1] = (f16)b;
    return u.i;
}

union Frag { f16x8 v; int i[4]; };

#define MFMA32(A, Bx, Cc) __builtin_amdgcn_mfma_f32_32x32x16_f16((A), (Bx), (Cc), 0, 0, 0)

// async global -> LDS, 4B per lane; LDS dest = wave-uniform base + lane*4
__device__ __forceinline__ void gload4(const void* g, void* lds) {
    typedef const unsigned int __attribute__((address_space(1))) as1u;
    typedef unsigned int __attribute__((address_space(3))) as3u;
    __builtin_amdgcn_global_load_lds((as1u*)g,
                                     (as3u*)(unsigned int)(unsigned long long)lds,
                                     4, 0, 0);
}

// ---------------------------------------------------------------------------
// QKV 1x1 conv -> packed f16 workspace.
// Q,K: half2 pair-words q2/k2[b][h][dp=0..11][L]  (Q pre-scaled by 8^-0.5)
// V:   plain f16        v16[b][h][d=0..23][L]
// ---------------------------------------------------------------------------
__global__ __launch_bounds__(256) void lin_qkv(const float* __restrict__ a,
                                               const float* __restrict__ w,
                                               const float* __restrict__ bias,
                                               unsigned int* __restrict__ q2,
                                               unsigned int* __restrict__ k2,
                                               unsigned short* __restrict__ v16) {
    __shared__ float wl[8][C_];
    const int og  = blockIdx.x;          // 0..71 (8 out-channels each)
    const int b   = blockIdx.y >> 4;
    const int lt  = blockIdx.y & 15;
    const int tid = threadIdx.x;

    for (int e = tid; e < 8 * C_; e += 256) wl[e / C_][e % C_] = w[og * 8 * C_ + e];
    __syncthreads();

    const int l = lt * 256 + tid;
    float acc[8];
#pragma unroll
    for (int j = 0; j < 8; ++j) acc[j] = bias[og * 8 + j];

    const float* ap = a + (size_t)b * C_ * L_ + l;
#pragma unroll 2
    for (int c = 0; c < C_; ++c) {
        const float xv = ap[(size_t)c * L_];
#pragma unroll
        for (int j = 0; j < 8; ++j) acc[j] = fmaf(wl[j][c], xv, acc[j]);
    }

    const float scale = 0.35355339059327373f;  // num_heads^-0.5
    if (og < 48) {
        unsigned int* dst = (og < 24) ? q2 : k2;
        const int og_ = (og < 24) ? og : og - 24;
        const float sc = (og < 24) ? scale : 1.f;
        const int h = og_ / 3, j0 = (og_ % 3) * 4;
        unsigned int* p = dst + ((size_t)(b * NH_ + h) * 12 + j0) * L_ + l;
#pragma unroll
        for (int j = 0; j < 4; ++j)
            p[(size_t)j * L_] = pk2_rte(acc[2 * j] * sc, acc[2 * j + 1] * sc);
    } else {
        const int og_ = og - 48;
        const int h = og_ / 3, d0 = (og_ % 3) * 8;
        unsigned short* p = v16 + ((size_t)(b * NH_ + h) * 24 + d0) * L_ + l;
#pragma unroll
        for (int j = 0; j < 8; ++j) {
            union { f16 hf; unsigned short us; } cv;
            cv.hf = (f16)acc[j];
            p[(size_t)j * L_] = cv.us;
        }
    }
}

// ---------------------------------------------------------------------------
// f32 per-pixel linear (output projection)
// ---------------------------------------------------------------------------
__global__ __launch_bounds__(256) void lin_kernel(const float* __restrict__ a,
                                                  const float* __restrict__ w,
                                                  const float* __restrict__ bias,
                                                  float* __restrict__ out, int OC) {
    __shared__ float wl[8][C_];
    const int og  = blockIdx.x;
    const int b   = blockIdx.y >> 4;
    const int lt  = blockIdx.y & 15;
    const int tid = threadIdx.x;

    for (int e = tid; e < 8 * C_; e += 256) wl[e / C_][e % C_] = w[og * 8 * C_ + e];
    __syncthreads();

    const int l = lt * 256 + tid;
    float acc[8];
#pragma unroll
    for (int j = 0; j < 8; ++j) acc[j] = bias[og * 8 + j];

    const float* ap = a + (size_t)b * C_ * L_ + l;
#pragma unroll 2
    for (int c = 0; c < C_; ++c) {
        const float xv = ap[(size_t)c * L_];
#pragma unroll
        for (int j = 0; j < 8; ++j) acc[j] = fmaf(wl[j][c], xv, acc[j]);
    }

    float* op = out + ((size_t)b * OC + og * 8) * L_ + l;
#pragma unroll
    for (int j = 0; j < 8; ++j) op[(size_t)j * L_] = acc[j];
}

// ---------------------------------------------------------------------------
// MFMA f16 flash attention. KVBLK=64, double-buffered LDS via global_load_lds,
// one barrier per tile, mask reg-prefetch, defer-max (THR=8).
// grid flat 512: bid = h*64 + b*32 + qt  (8 heads of a qtile share bid%8 = XCD)
// ---------------------------------------------------------------------------
__global__ __launch_bounds__(256) void attn_mfma(const unsigned int* __restrict__ q2,
                                                 const unsigned int* __restrict__ k2,
                                                 const unsigned short* __restrict__ v16,
                                                 const float* __restrict__ mask,
                                                 float* __restrict__ out) {
    const int tid  = threadIdx.x;
    const int lane = tid & 63;
    const int wid  = tid >> 6;
    const int hi   = lane >> 5;
    const int lq   = lane & 31;
    const int bid  = blockIdx.x;
    const int h    = bid >> 6;
    const int b    = (bid >> 5) & 1;
    const int qt   = bid & 31;
    const int qrow = qt * 128 + wid * 32 + lq;

    __shared__ int k_lds[2][16][64];   // rows 12..15 zeroed (K pad, contraction dim)
    __shared__ int v_lds[2][32][32];   // rows 24..31 garbage (isolated to unread O rows)

    {   // zero K pad rows once; staging never touches them
        const int r = 12 + (tid >> 6), c0 = tid & 63;
        k_lds[0][r][c0] = 0;
        k_lds[1][r][c0] = 0;
    }

    const unsigned int*   qb = q2  + (size_t)(b * NH_ + h) * 12 * L_;
    const unsigned int*   kb = k2  + (size_t)(b * NH_ + h) * 12 * L_;
    const unsigned short* vb = v16 + (size_t)(b * NH_ + h) * 24 * L_;
    const float* mrow = mask + ((size_t)b * L_ + qrow) * L_;

    // Q fragments (pair-words; zero where dpq >= 12)
    int bq[8];
#pragma unroll
    for (int s = 0; s < 2; ++s)
#pragma unroll
        for (int t = 0; t < 4; ++t) {
            const int dpq = 8 * s + 4 * hi + t;
            bq[s * 4 + t] = (dpq < 12) ? qb[(size_t)dpq * L_ + qrow] : 0;
        }

    // staging sources (advance KV_ elements per tile); LDS offsets wave-uniform
    const unsigned int*   kg[3];
    const unsigned short* vg[3];
    int kls[3], vls[3];
#pragma unroll
    for (int i = 0; i < 3; ++i) {
        const int e = i * 256 + tid;
        kg[i]  = kb + (size_t)(e >> 6) * L_ + (e & 63);
        kls[i] = i * 256 + 64 * wid;
        const int d = e >> 5, slot = e & 31;
        vg[i]  = vb + (size_t)d * L_ + 2 * (slot ^ d);   // XOR pre-swizzled source
        vls[i] = i * 256 + 64 * wid;
    }

#define STAGE(BUF, KK) do {                                                   \
    _Pragma("unroll")                                                         \
    for (int i_ = 0; i_ < 3; ++i_) {                                          \
        gload4(kg[i_] + (KK), &k_lds[BUF][0][0] + kls[i_]);                   \
        gload4(vg[i_] + (KK), &v_lds[BUF][0][0] + vls[i_]);                   \
    } } while (0)

#define MLOAD(MD, KK) do {                                                    \
    const float4* mb_ = (const float4*)(mrow + (KK));                         \
    _Pragma("unroll")                                                         \
    for (int u_ = 0; u_ < 2; ++u_)                                            \
        _Pragma("unroll")                                                     \
        for (int q_ = 0; q_ < 4; ++q_)                                        \
            MD[u_ * 4 + q_] = mb_[8 * u_ + 2 * q_ + hi];                      \
    } while (0)

#define PVSTEP(CU, U) do {                                                    \
    int w1[4], w2[4], s1[4], s2[4];                                           \
    _Pragma("unroll")                                                         \
    for (int q_ = 0; q_ < 4; ++q_) {                                          \
        w1[q_] = pk2(CU[4 * q_], CU[4 * q_ + 1]);                             \
        w2[q_] = pk2(CU[4 * q_ + 2], CU[4 * q_ + 3]);                         \
    }                                                                         \
    _Pragma("unroll")                                                         \
    for (int q_ = 0; q_ < 4; ++q_) {                                          \
        s1[q_] = __shfl_xor(w1[q_], 32);                                      \
        s2[q_] = __shfl_xor(w2[q_], 32);                                      \
    }                                                                         \
    _Pragma("unroll")                                                         \
    for (int s_ = 0; s_ < 2; ++s_) {                                          \
        const int qq_ = 2 * s_ + hi;                                          \
        Frag pb, va;                                                          \
        pb.i[0] = hi ? s1[qq_] : w1[qq_];                                     \
        pb.i[1] = hi ? s2[qq_] : w2[qq_];                                     \
        pb.i[2] = hi ? w1[qq_] : s1[qq_];                                     \
        pb.i[3] = hi ? w2[qq_] : s2[qq_];                                     \
        _Pragma("unroll")                                                     \
        for (int t_ = 0; t_ < 4; ++t_)                                        \
            va.i[t_] = v_lds[BUF_ACTIVE][lq][(16 * U + 8 * s_ + 4 * hi + t_) ^ lq]; \
        o = MFMA32(va.v, pb.v, o);                                            \
    } } while (0)

#define COMPUTE(BUF, MC) do {                                                 \
    const int BUF_ACTIVE = (BUF);                                             \
    f32x16 c0, c1;                                                            \
    c0[0] = MC[0].x; c0[1] = MC[0].y; c0[2]  = MC[0].z; c0[3]  = MC[0].w;     \
    c0[4] = MC[1].x; c0[5] = MC[1].y; c0[6]  = MC[1].z; c0[7]  = MC[1].w;     \
    c0[8] = MC[2].x; c0[9] = MC[2].y; c0[10] = MC[2].z; c0[11] = MC[2].w;     \
    c0[12] = MC[3].x; c0[13] = MC[3].y; c0[14] = MC[3].z; c0[15] = MC[3].w;   \
    c1[0] = MC[4].x; c1[1] = MC[4].y; c1[2]  = MC[4].z; c1[3]  = MC[4].w;     \
    c1[4] = MC[5].x; c1[5] = MC[5].y; c1[6]  = MC[5].z; c1[7]  = MC[5].w;     \
    c1[8] = MC[6].x; c1[9] = MC[6].y; c1[10] = MC[6].z; c1[11] = MC[6].w;     \
    c1[12] = MC[7].x; c1[13] = MC[7].y; c1[14] = MC[7].z; c1[15] = MC[7].w;   \
    Frag qf0, qf1, ka0, ka1;                                                  \
    _Pragma("unroll")                                                         \
    for (int t_ = 0; t_ < 4; ++t_) { qf0.i[t_] = bq[t_]; qf1.i[t_] = bq[4 + t_]; } \
    _Pragma("unroll")                                                         \
    for (int t_ = 0; t_ < 4; ++t_) {                                          \
        ka0.i[t_] = k_lds[BUF_ACTIVE][4 * hi + t_][lq];                       \
        ka1.i[t_] = k_lds[BUF_ACTIVE][8 + 4 * hi + t_][lq];                   \
    }                                                                         \
    c0 = MFMA32(ka0.v, qf0.v, c0);                                            \
    c0 = MFMA32(ka1.v, qf1.v, c0);                                            \
    _Pragma("unroll")                                                         \
    for (int t_ = 0; t_ < 4; ++t_) {                                          \
        ka0.i[t_] = k_lds[BUF_ACTIVE][4 * hi + t_][32 + lq];                  \
        ka1.i[t_] = k_lds[BUF_ACTIVE][8 + 4 * hi + t_][32 + lq];              \
    }                                                                         \
    c1 = MFMA32(ka0.v, qf0.v, c1);                                            \
    c1 = MFMA32(ka1.v, qf1.v, c1);                                            \
    float pmax = c0[0];                                                       \
    _Pragma("unroll")                                                         \
    for (int i_ = 1; i_ < 16; ++i_) pmax = fmaxf(pmax, c0[i_]);               \
    _Pragma("unroll")                                                         \
    for (int i_ = 0; i_ < 16; ++i_) pmax = fmaxf(pmax, c1[i_]);               \
    pmax = fmaxf(pmax, __shfl_xor(pmax, 32));                                 \
    if (!__all(pmax <= mrun + 8.f)) {                                         \
        const float newm_ = fmaxf(mrun, pmax);                                \
        const float r_ = __expf(mrun - newm_);                                \
        srun *= r_;                                                           \
        _Pragma("unroll")                                                     \
        for (int i_ = 0; i_ < 16; ++i_) o[i_] *= r_;                          \
        mrun = newm_;                                                         \
    }                                                                         \
    float ls = 0.f;                                                           \
    _Pragma("unroll")                                                         \
    for (int i_ = 0; i_ < 16; ++i_) { c0[i_] = __expf(c0[i_] - mrun); ls += c0[i_]; } \
    _Pragma("unroll")                                                         \
    for (int i_ = 0; i_ < 16; ++i_) { c1[i_] = __expf(c1[i_] - mrun); ls += c1[i_]; } \
    ls += __shfl_xor(ls, 32);                                                 \
    srun += ls;                                                               \
    PVSTEP(c0, 0);                                                            \
    PVSTEP(c1, 1);                                                            \
    } while (0)

    f32x16 o;
#pragma unroll
    for (int i = 0; i < 16; ++i) o[i] = 0.f;
    float mrun = -1e30f, srun = 0.f;
    float4 mc[8], mn[8];

    STAGE(0, 0);
    MLOAD(mc, 0);
    __syncthreads();   // drains vmcnt before barrier

    for (int t = 0; t < NT_; t += 2) {
        const int kk = t * KV_;
        STAGE(1, kk + KV_);
        MLOAD(mn, kk + KV_);
        COMPUTE(0, mc);
        __syncthreads();
        if (t + 2 < NT_) {
            STAGE(0, kk + 2 * KV_);
            MLOAD(mc, kk + 2 * KV_);
        }
        COMPUTE(1, mn);
        __syncthreads();
    }

    const float inv = 1.f / srun;
    float* op = out + ((size_t)b * C_ + h * HD_) * L_ + qrow;
#pragma unroll
    for (int i = 0; i < 16; ++i) {
        const int d = (i & 3) + 8 * (i >> 2) + 4 * hi;
        if (d < HD_) op[(size_t)d * L_] = o[i] * inv;
    }
#undef STAGE
#undef MLOAD
#undef PVSTEP
#undef COMPUTE
}

// ---------------------------------------------------------------------------
extern "C" void kernel_launch(void* const* d_in, const int* in_sizes, int n_in,
                              void* d_out, int out_size, void* d_ws, size_t ws_size,
                              hipStream_t stream) {
    const float* x      = (const float*)d_in[0];
    const float* mask   = (const float*)d_in[1];
    const float* w_qkv  = (const float*)d_in[2];
    const float* b_qkv  = (const float*)d_in[3];
    const float* w_proj = (const float*)d_in[4];
    const float* b_proj = (const float*)d_in[5];
    float* out = (float*)d_out;

    unsigned int*   q2  = (unsigned int*)d_ws;                    // B*8*12*L u32
    unsigned int*   k2  = q2 + (size_t)B_ * NH_ * 12 * L_;        // B*8*12*L u32
    unsigned short* v16 = (unsigned short*)(k2 + (size_t)B_ * NH_ * 12 * L_);  // B*8*24*L u16
    float* ws_att = (float*)(v16 + (size_t)B_ * NH_ * 24 * L_);   // B*192*L f32

    lin_qkv<<<dim3(72, 32), 256, 0, stream>>>(x, w_qkv, b_qkv, q2, k2, v16);
    attn_mfma<<<dim3(512), 256, 0, stream>>>(q2, k2, v16, mask, ws_att);
    lin_kernel<<<dim3(24, 32), 256, 0, stream>>>(ws_att, w_proj, b_proj, out, C_);
}